// Round 12
// baseline (37.761 us; speedup 1.0000x reference)
//
#include <hip/hip_runtime.h>
#include <hip/hip_bf16.h>

// Problem constants
static constexpr int FEAT_  = 3136;          // K of GEMM1 (= 98 ksteps of 32)
static constexpr int KSTEPS = 98;
static constexpr int RSTR   = 300;           // x row stride (proposals per batch)
static constexpr int SROWS  = 128;           // SELECTED_PROPOSAL
static constexpr int HID    = 64;            // hidden
static constexpr int NCLS   = 21;            // classes
static constexpr int BM     = 32;            // rows per block
static constexpr int KC     = 448;           // K-floats per staging chunk (14 ksteps)
static constexpr int NCHUNK = FEAT_ / KC;    // 7  (exact: 7*448 = 3136)
static constexpr int KSPC   = KC / 32;       // 14 ksteps per chunk
static constexpr int ROWB   = KC * 2;        // LDS row stride in bytes (896)

typedef __attribute__((ext_vector_type(8))) short bf16x8;
typedef __attribute__((ext_vector_type(4))) float f32x4;

// W1 packed in natural MFMA B-fragment order: elem j <-> k = ks*32 + (lane>>4)*8 + j
__device__ bf16x8 g_w1p[KSTEPS * 4 * 64];

__global__ __launch_bounds__(256) void pack_w1(const float* __restrict__ W1) {
    int t = blockIdx.x * 256 + threadIdx.x;        // 0 .. 25087
    int lane = t & 63;
    int nt   = (t >> 6) & 3;
    int ks   = t >> 8;
    int col  = nt * 16 + (lane & 15);
    int k0   = ks * 32 + (lane >> 4) * 8;
    union { bf16x8 v; __hip_bfloat16 h[8]; } u;
    #pragma unroll
    for (int j = 0; j < 8; ++j)
        u.h[j] = __float2bfloat16(W1[(k0 + j) * HID + col]);
    g_w1p[t] = u.v;
}

__device__ __forceinline__ uint2 pack4(f32x4 v) {
    union { uint2 u; __hip_bfloat162 h[2]; } q;
    q.h[0] = __float22bfloat162_rn(make_float2(v[0], v[1]));
    q.h[1] = __float22bfloat162_rn(make_float2(v[2], v[3]));
    return q.u;
}

// One block = 32 rows, 512 threads = 8 waves = 2 m-tiles x 4 n-quarters.
// x is staged through LDS in 256B-contiguous bursts (each thread owns one
// row; 16 lanes cover 256B), converted to bf16 once, XOR-swizzled for
// near-conflict-free 16B A-frag reads. 2-chunk register prefetch pipeline.
__global__ __launch_bounds__(512) void fused_main(
    const float* __restrict__ x,  const float* __restrict__ b1,
    const float* __restrict__ W2, const float* __restrict__ b2,
    const int*  __restrict__ keep, float* __restrict__ out)
{
    const int tid  = threadIdx.x;
    const int lane = tid & 63;
    const int wv   = tid >> 6;        // 0..7
    const int mt   = wv >> 2;         // m-tile (0/1)
    const int nq   = wv & 3;          // n-quarter
    const int row_base = blockIdx.x * BM;      // flat (b*128 + s) row
    const int b      = row_base >> 7;
    const int s_base = row_base & 127;

    float* outp = out + row_base * NCLS;
    const int limit = min(keep[b], SROWS);

    // Whole 32-row group masked out -> just write zeros, skip all loads.
    if (s_base >= limit) {
        for (int i = tid; i < BM * NCLS; i += 512) outp[i] = 0.f;
        return;
    }

    __shared__ __hip_bfloat16 xs[2][BM][KC];   // 2 x 28 KB, XOR-swizzled
    __shared__ float hf[BM][HID + 2];          // h (post bias+leaky)
    __shared__ float w2s[HID * NCLS];

    for (int i = tid; i < HID * NCLS; i += 512) w2s[i] = W2[i];

    // ---- staging: thread -> one row (r_loc = 4*wv + lane>>4), 16 lanes/row ----
    const int r_loc = 4 * wv + (lane >> 4);
    const int l16   = lane & 15;
    // Masked rows clamp to limit-1 (duplicate addresses -> L1 hits).
    const long rg = (long)(b * RSTR + min(s_base + r_loc, limit - 1)) * FEAT_ + l16 * 4;

    auto issue = [&](int c, f32x4* rr) {
        #pragma unroll
        for (int i = 0; i < 7; ++i)
            rr[i] = *(const f32x4*)(x + rg + c * KC + i * 64);
    };
    auto cvtwrite = [&](int c, f32x4* rr) {
        char* base = (char*)&xs[c & 1][0][0];
        const unsigned ro = (unsigned)(r_loc * ROWB) ;
        const unsigned sz = (unsigned)((r_loc & 7) << 4);
        #pragma unroll
        for (int i = 0; i < 7; ++i) {
            unsigned off = (ro + l16 * 8 + i * 128) ^ sz;
            *(uint2*)(base + off) = pack4(rr[i]);
        }
    };

    f32x4 acc = {0.f, 0.f, 0.f, 0.f};
    const int arow = mt * 16 + (lane & 15);            // A-frag row in tile
    const unsigned abase = (unsigned)(arow * ROWB + ((lane >> 4) * 16));
    const unsigned aswz  = (unsigned)((arow & 7) << 4);

    auto compute = [&](int c) {
        const char* base = (const char*)&xs[c & 1][0][0];
        const bf16x8* wpc = g_w1p + (c * KSPC * 4 + nq) * 64 + lane;
        #pragma unroll
        for (int ks = 0; ks < KSPC; ++ks) {
            bf16x8 av = *(const bf16x8*)(base + ((abase + ks * 64) ^ aswz));
            acc = __builtin_amdgcn_mfma_f32_16x16x32_bf16(av, wpc[ks * 256], acc, 0, 0, 0);
        }
    };

    // ---- software pipeline: 2-chunk register prefetch, 2 LDS buffers ----
    f32x4 rA[7], rB[7];
    issue(0, rA);
    issue(1, rB);
    cvtwrite(0, rA);
    __syncthreads();

    int c = 0;
    for (; c + 1 < NCHUNK; c += 2) {              // c = 0, 2, 4
        if (c + 2 < NCHUNK) issue(c + 2, rA);
        cvtwrite(c + 1, rB);
        compute(c);
        __syncthreads();
        if (c + 3 < NCHUNK) issue(c + 3, rB);
        if (c + 2 < NCHUNK) cvtwrite(c + 2, rA);
        compute(c + 1);
        __syncthreads();
    }
    compute(c);                                   // c == 6, already staged

    // ---- epilogue: bias + leaky -> hf; then GEMM2 ----
    // D layout: col = lane&15 (+16*nq), row = mt*16 + (lane>>4)*4 + rr
    const int cg = nq * 16 + (lane & 15);
    const int r0 = mt * 16 + (lane >> 4) * 4;
    const float b1v = b1[cg];
    #pragma unroll
    for (int rr = 0; rr < 4; ++rr) {
        float v = acc[rr] + b1v;
        hf[r0 + rr][cg] = (v >= 0.f) ? v : 0.1f * v;   // leaky relu #1
    }
    __syncthreads();

    // GEMM2: [32 x 64] @ [64 x 21] + b2, leaky, keep_count mask
    for (int idx = tid; idx < BM * NCLS; idx += 512) {
        int rI = idx / NCLS;
        int cI = idx - rI * NCLS;
        float a2 = b2[cI];
        #pragma unroll 8
        for (int col = 0; col < HID; ++col)
            a2 += hf[rI][col] * w2s[col * NCLS + cI];
        a2 = (a2 >= 0.f) ? a2 : 0.1f * a2;             // leaky relu #2
        outp[idx] = (s_base + rI < limit) ? a2 : 0.f;
    }
}

extern "C" void kernel_launch(void* const* d_in, const int* in_sizes, int n_in,
                              void* d_out, int out_size, void* d_ws, size_t ws_size,
                              hipStream_t stream) {
    const float* x    = (const float*)d_in[0];
    const float* W1   = (const float*)d_in[1];
    const float* b1   = (const float*)d_in[2];
    const float* W2   = (const float*)d_in[3];
    const float* b2   = (const float*)d_in[4];
    const int*   keep = (const int*)d_in[5];
    float* out = (float*)d_out;

    hipLaunchKernelGGL(pack_w1,    dim3(KSTEPS), dim3(256), 0, stream, W1);
    hipLaunchKernelGGL(fused_main, dim3((64 * SROWS) / BM), dim3(512), 0, stream,
                       x, b1, W2, b2, keep, out);
}